// Round 2
// baseline (56048.499 us; speedup 1.0000x reference)
//
#include <hip/hip_runtime.h>
#include <math.h>

#define BB 32
#define TT 500
#define HH 640
#define VV 1024
#define NWG 256

// ws layout (float offsets)
//  ENC    : 0           (16000*640 = 10,240,000)
//  EW     : 10,240,000  (1024*2560 =  2,621,440)
//  h      : 12,861,440  (32*640)
//  c      : 12,881,920  (32*640)
//  Tt     : 12,902,400  (32*640)
//  G      : 12,922,880  (32*2560 -> ends 13,004,800)
//  pmax   : 13,004,800  (32*256 u64 = 16,384 floats)
//  psum   : 13,021,184  (32*256 = 8,192 floats)
//  scores : 13,029,376  (32)
//  arrive : 13,029,440  (256 uints)
//  release: 13,029,696  (16)
// total 13,029,712 floats = 52.12 MB

__device__ __forceinline__ float sigf(float x) { return 1.0f / (1.0f + expf(-x)); }

__device__ __forceinline__ unsigned int fkey(float x) {
    unsigned int u = __float_as_uint(x);
    return (u & 0x80000000u) ? ~u : (u | 0x80000000u);
}

__device__ __forceinline__ unsigned long long shflxor_u64(unsigned long long v, int m) {
    unsigned int lo = (unsigned int)v, hi = (unsigned int)(v >> 32);
    lo = (unsigned int)__shfl_xor((int)lo, m);
    hi = (unsigned int)__shfl_xor((int)hi, m);
    return ((unsigned long long)hi << 32) | lo;
}

// distributed-flag grid barrier; all NWG WGs must call with same k sequence
__device__ __forceinline__ void gbar(unsigned int* arrive, unsigned int* release,
                                     int w, int tid, unsigned int k) {
    __syncthreads();
    if (tid == 0) {
        __threadfence();
        __hip_atomic_store(&arrive[w], k, __ATOMIC_RELEASE, __HIP_MEMORY_SCOPE_AGENT);
    }
    if (w == 0) {
        while (__hip_atomic_load(&arrive[tid], __ATOMIC_ACQUIRE, __HIP_MEMORY_SCOPE_AGENT) < k) {}
        __syncthreads();
        if (tid == 0)
            __hip_atomic_store(release, k, __ATOMIC_RELEASE, __HIP_MEMORY_SCOPE_AGENT);
    } else {
        if (tid == 0) {
            while (__hip_atomic_load(release, __ATOMIC_ACQUIRE, __HIP_MEMORY_SCOPE_AGENT) < k) {}
            __threadfence();
        }
        __syncthreads();
    }
}

// C[M,N] = A[M,K] @ B[K,N] + bias[N]   (row-major f32)
__global__ __launch_bounds__(256) void gemm_bias_kernel(
    const float* __restrict__ A, const float* __restrict__ Bm,
    const float* __restrict__ bias, float* __restrict__ C,
    int M, int N, int K)
{
    __shared__ float As[16][65];
    __shared__ float Bs[16][64];
    int tid = threadIdx.x;
    int m0 = blockIdx.y * 64, n0 = blockIdx.x * 64;
    int ar = tid >> 2, ac = (tid & 3) * 4;
    int br4 = (tid >> 6) * 4, bc = tid & 63;
    int ty = tid >> 4, tx = tid & 15;
    float acc[4][4] = {};
    for (int k0 = 0; k0 < K; k0 += 16) {
        float4 av = *(const float4*)(A + (long)(m0 + ar) * K + k0 + ac);
        As[ac + 0][ar] = av.x; As[ac + 1][ar] = av.y;
        As[ac + 2][ar] = av.z; As[ac + 3][ar] = av.w;
#pragma unroll
        for (int i = 0; i < 4; ++i)
            Bs[br4 + i][bc] = Bm[(long)(k0 + br4 + i) * N + n0 + bc];
        __syncthreads();
#pragma unroll
        for (int kk = 0; kk < 16; ++kk) {
            float a[4], b[4];
#pragma unroll
            for (int i = 0; i < 4; ++i) a[i] = As[kk][ty * 4 + i];
#pragma unroll
            for (int j = 0; j < 4; ++j) b[j] = Bs[kk][tx * 4 + j];
#pragma unroll
            for (int i = 0; i < 4; ++i)
#pragma unroll
                for (int j = 0; j < 4; ++j)
                    acc[i][j] = fmaf(a[i], b[j], acc[i][j]);
        }
        __syncthreads();
    }
#pragma unroll
    for (int i = 0; i < 4; ++i)
#pragma unroll
        for (int j = 0; j < 4; ++j)
            C[(long)(m0 + ty * 4 + i) * N + n0 + tx * 4 + j] =
                acc[i][j] + bias[n0 + tx * 4 + j];
}

// init h,c from BLANK token with zero state; zero scores + barrier flags
__global__ void init_kernel(const float* __restrict__ EW, float* __restrict__ h,
                            float* __restrict__ c, float* __restrict__ scores,
                            unsigned int* __restrict__ arrive,
                            unsigned int* __restrict__ release)
{
    int tid = threadIdx.x;
    for (int j = tid; j < HH; j += 256) {
        float gi = EW[j], gg = EW[1280 + j], go = EW[1920 + j];
        float c1 = sigf(gi) * tanhf(gg);
        float h1 = sigf(go) * tanhf(c1);
        for (int b = 0; b < BB; ++b) { h[b * 640 + j] = h1; c[b * 640 + j] = c1; }
    }
    if (tid < 32) scores[tid] = 0.f;
    arrive[tid] = 0u;
    if (tid == 0) release[0] = 0u;
}

__global__ __launch_bounds__(256, 1) void decode_kernel(
    const float* __restrict__ ENC, const float* __restrict__ EW,
    const float* __restrict__ Wdec, const float* __restrict__ Whh,
    const float* __restrict__ Wout, const float* __restrict__ bout,
    float* __restrict__ h, float* __restrict__ c,
    float* __restrict__ Tt, float* __restrict__ G,
    unsigned long long* __restrict__ pmax, float* __restrict__ psum,
    float* __restrict__ scores, float* __restrict__ out,
    unsigned int* arrive, unsigned int* release)
{
    __shared__ float Wa[640 * 16];          // 40 KB: 16 cols of [W_dec|W_hh], layout [k][16]
    __shared__ float Wo[640 * 4];           // 10 KB: 4 cols of W_out, layout [k][4]
    __shared__ unsigned long long red_m[4];
    __shared__ float red_s[4];
    __shared__ int s_tok, s_emit;

    int w = blockIdx.x, tid = threadIdx.x;

    // ---- stage weights to LDS (once) ----
    if (w < 200) {
        if (w < 40) {
            const float* src = Wdec + w * 16;
            for (int i = tid; i < 640 * 16; i += 256) {
                int k = i >> 4, cc = i & 15;
                Wa[i] = src[k * 640 + cc];
            }
        } else {
            const float* src = Whh + (w * 16 - 640);
            for (int i = tid; i < 640 * 16; i += 256) {
                int k = i >> 4, cc = i & 15;
                Wa[i] = src[k * 2560 + cc];
            }
        }
    }
    {
        const float* src = Wout + w * 4;
        for (int i = tid; i < 640 * 4; i += 256) {
            int k = i >> 2, cc = i & 3;
            Wo[i] = src[k * 1024 + cc];
        }
    }
    __syncthreads();

    unsigned int bk = 0;

    for (int t = 0; t < TT; ++t) {
        // ---- Phase A: u = h @ [W_dec|W_hh]; Tt = tanh(ENC+u_dec), G = u_hh ----
        if (w < 200) {
            int b = tid >> 3, cg = tid & 7;
            int lc = cg * 2;
            const float* hb = h + b * 640;
            float a0 = 0.f, a1 = 0.f;
            for (int k0 = 0; k0 < 640; k0 += 4) {
                float4 hv = *(const float4*)(hb + k0);
                float hl[4] = {hv.x, hv.y, hv.z, hv.w};
#pragma unroll
                for (int j = 0; j < 4; ++j) {
                    float2 wv = *(const float2*)(&Wa[(k0 + j) * 16 + lc]);
                    a0 = fmaf(hl[j], wv.x, a0);
                    a1 = fmaf(hl[j], wv.y, a1);
                }
            }
            int gc = w * 16 + lc;
            if (gc < 640) {
                const float* e = ENC + ((long)b * TT + t) * 640;
                Tt[b * 640 + gc]     = tanhf(e[gc] + a0);
                Tt[b * 640 + gc + 1] = tanhf(e[gc + 1] + a1);
            } else {
                G[b * 2560 + gc - 640]     = a0;
                G[b * 2560 + gc - 640 + 1] = a1;
            }
        }
        gbar(arrive, release, w, tid, ++bk);

        // ---- Phase B: logits slice + per-WG argmax/sumexp partials ----
        {
            int half = tid & 1, p = tid >> 1, b = p >> 2, cl = p & 3;
            const float* tb = Tt + b * 640 + half * 320;
            const float* wb = Wo + half * 1280 + cl;
            float acc = 0.f;
            for (int k0 = 0; k0 < 320; k0 += 4) {
                float4 tv = *(const float4*)(tb + k0);
                acc = fmaf(tv.x, wb[(k0 + 0) * 4], acc);
                acc = fmaf(tv.y, wb[(k0 + 1) * 4], acc);
                acc = fmaf(tv.z, wb[(k0 + 2) * 4], acc);
                acc = fmaf(tv.w, wb[(k0 + 3) * 4], acc);
            }
            float oth = __shfl_xor(acc, 1);
            int col = w * 4 + cl;
            float logit = acc + oth + bout[col];
            float sexp = expf(logit);
            unsigned long long pk =
                ((unsigned long long)fkey(logit) << 32) | (unsigned int)(1023 - col);
            unsigned long long o;
            o = shflxor_u64(pk, 2); if (o > pk) pk = o; sexp += __shfl_xor(sexp, 2);
            o = shflxor_u64(pk, 4); if (o > pk) pk = o; sexp += __shfl_xor(sexp, 4);
            if ((tid & 7) == 0) {
                pmax[b * 256 + w] = pk;
                psum[b * 256 + w] = sexp;
            }
        }
        gbar(arrive, release, w, tid, ++bk);

        // ---- Phase C: reduce partials, emit token, LSTM update ----
        if (w < 32) {
            int b = w;
            unsigned long long m = pmax[b * 256 + tid];
            float s = psum[b * 256 + tid];
#pragma unroll
            for (int mask = 1; mask <= 32; mask <<= 1) {
                unsigned long long o = shflxor_u64(m, mask);
                if (o > m) m = o;
                s += __shfl_xor(s, mask);
            }
            if ((tid & 63) == 0) { red_m[tid >> 6] = m; red_s[tid >> 6] = s; }
            __syncthreads();
            if (tid == 0) {
                unsigned long long mm = red_m[0];
                float ss = red_s[0];
#pragma unroll
                for (int i = 1; i < 4; ++i) {
                    if (red_m[i] > mm) mm = red_m[i];
                    ss += red_s[i];
                }
                int tok = 1023 - (int)(mm & 0xFFFFFFFFu);
                unsigned int key = (unsigned int)(mm >> 32);
                unsigned int u = (key & 0x80000000u) ? (key ^ 0x80000000u) : ~key;
                float maxlogit = __uint_as_float(u);
                int emit = (tok != 0);
                out[b * TT + t] = (float)tok;
                if (emit) scores[b] += maxlogit - logf(ss);
                s_tok = tok; s_emit = emit;
            }
            __syncthreads();
            if (s_emit) {
                const float* ew = EW + (long)s_tok * 2560;
                const float* gb = G + b * 2560;
                for (int j = tid; j < 640; j += 256) {
                    float gi = ew[j] + gb[j];
                    float gf = ew[640 + j] + gb[640 + j];
                    float gg = ew[1280 + j] + gb[1280 + j];
                    float go = ew[1920 + j] + gb[1920 + j];
                    float cn = sigf(gf) * c[b * 640 + j] + sigf(gi) * tanhf(gg);
                    float hn = sigf(go) * tanhf(cn);
                    c[b * 640 + j] = cn;
                    h[b * 640 + j] = hn;
                }
            }
        }
        gbar(arrive, release, w, tid, ++bk);
    }

    if (w == 0 && tid == 0) {
        float s = 0.f;
        for (int b = 0; b < 32; ++b) s += expf(scores[b]);
        out[16000] = s / 32.0f;
    }
}

extern "C" void kernel_launch(void* const* d_in, const int* in_sizes, int n_in,
                              void* d_out, int out_size, void* d_ws, size_t ws_size,
                              hipStream_t stream)
{
    const float* X     = (const float*)d_in[0];
    const float* E     = (const float*)d_in[1];
    const float* W_ih  = (const float*)d_in[2];
    const float* W_hh  = (const float*)d_in[3];
    const float* b_l   = (const float*)d_in[4];
    const float* W_enc = (const float*)d_in[5];
    const float* W_dec = (const float*)d_in[6];
    const float* b_j   = (const float*)d_in[7];
    const float* W_out = (const float*)d_in[8];
    const float* b_out = (const float*)d_in[9];

    float* ws  = (float*)d_ws;
    float* ENC = ws;
    float* EW  = ws + 10240000;
    float* h   = ws + 12861440;
    float* c   = ws + 12881920;
    float* Tt  = ws + 12902400;
    float* G   = ws + 12922880;
    unsigned long long* pmax = (unsigned long long*)(ws + 13004800);
    float* psum   = ws + 13021184;
    float* scores = ws + 13029376;
    unsigned int* arrive  = (unsigned int*)(ws + 13029440);
    unsigned int* release = (unsigned int*)(ws + 13029696);
    float* out = (float*)d_out;

    gemm_bias_kernel<<<dim3(10, 250), 256, 0, stream>>>(X, W_enc, b_j, ENC, 16000, 640, 640);
    gemm_bias_kernel<<<dim3(40, 16), 256, 0, stream>>>(E, W_ih, b_l, EW, 1024, 2560, 640);
    init_kernel<<<1, 256, 0, stream>>>(EW, h, c, scores, arrive, release);

    void* args[] = {
        (void*)&ENC, (void*)&EW, (void*)&W_dec, (void*)&W_hh,
        (void*)&W_out, (void*)&b_out, (void*)&h, (void*)&c,
        (void*)&Tt, (void*)&G, (void*)&pmax, (void*)&psum,
        (void*)&scores, (void*)&out, (void*)&arrive, (void*)&release
    };
    hipLaunchCooperativeKernel((const void*)decode_kernel, dim3(NWG), dim3(256),
                               args, 0, stream);
}

// Round 3
// 25064.259 us; speedup vs baseline: 2.2362x; 2.2362x over previous
//
#include <hip/hip_runtime.h>
#include <math.h>

#define BB 32
#define TT 500
#define HH 640
#define VV 1024
#define NWG 256

// ws layout (float offsets)
//  ENC    : 0           (16000*640 = 10,240,000)
//  EW     : 10,240,000  (1024*2560 =  2,621,440)
//  h      : 12,861,440  (32*640)
//  c      : 12,881,920  (32*640)
//  Tt     : 12,902,400  (32*640)
//  G      : 12,922,880  (32*2560 -> ends 13,004,800)
//  pmax   : 13,004,800  (32*256 u64 = 16,384 floats)
//  psum   : 13,021,184  (32*256 = 8,192 floats)
//  scores : 13,029,376  (32, pad to 64)
//  arrive : 13,029,440  (256 slots x 32 u32 = 8,192 floats, 128B-padded)
//  release: 13,037,632  (256 slots x 32 u32 = 8,192 floats)
// total 13,045,824 floats = 52.18 MB

__device__ __forceinline__ float sigf(float x) { return 1.0f / (1.0f + expf(-x)); }

__device__ __forceinline__ unsigned int fkey(float x) {
    unsigned int u = __float_as_uint(x);
    return (u & 0x80000000u) ? ~u : (u | 0x80000000u);
}

__device__ __forceinline__ unsigned long long shflxor_u64(unsigned long long v, int m) {
    unsigned int lo = (unsigned int)v, hi = (unsigned int)(v >> 32);
    lo = (unsigned int)__shfl_xor((int)lo, m);
    hi = (unsigned int)__shfl_xor((int)hi, m);
    return ((unsigned long long)hi << 32) | lo;
}

// Distributed grid barrier: 128B-padded per-WG arrive + per-WG release slots.
// WG0 threads gather arrivals (one line each) and fan out releases (one line
// each); every other WG touches only its own two lines. No shared hot line.
__device__ __forceinline__ void gbar(unsigned int* arrive, unsigned int* release,
                                     int w, int tid, unsigned int k) {
    __syncthreads();
    if (w == 0) {
        if (tid > 0) {
            while (__hip_atomic_load(&arrive[tid * 32], __ATOMIC_RELAXED,
                                     __HIP_MEMORY_SCOPE_AGENT) < k)
                __builtin_amdgcn_s_sleep(2);
        }
        __syncthreads();       // all 255 arrivals observed
        __threadfence();       // acquire their data; release WG0's own writes
        if (tid > 0)
            __hip_atomic_store(&release[tid * 32], k, __ATOMIC_RELAXED,
                               __HIP_MEMORY_SCOPE_AGENT);
        __syncthreads();
    } else {
        if (tid == 0) {
            __threadfence();   // release this WG's phase writes
            __hip_atomic_store(&arrive[w * 32], k, __ATOMIC_RELAXED,
                               __HIP_MEMORY_SCOPE_AGENT);
            while (__hip_atomic_load(&release[w * 32], __ATOMIC_RELAXED,
                                     __HIP_MEMORY_SCOPE_AGENT) < k)
                __builtin_amdgcn_s_sleep(2);
            __threadfence();   // acquire everyone's phase writes
        }
        __syncthreads();
    }
}

// C[M,N] = A[M,K] @ B[K,N] + bias[N]   (row-major f32)
__global__ __launch_bounds__(256) void gemm_bias_kernel(
    const float* __restrict__ A, const float* __restrict__ Bm,
    const float* __restrict__ bias, float* __restrict__ C,
    int M, int N, int K)
{
    __shared__ float As[16][65];
    __shared__ float Bs[16][64];
    int tid = threadIdx.x;
    int m0 = blockIdx.y * 64, n0 = blockIdx.x * 64;
    int ar = tid >> 2, ac = (tid & 3) * 4;
    int br4 = (tid >> 6) * 4, bc = tid & 63;
    int ty = tid >> 4, tx = tid & 15;
    float acc[4][4] = {};
    for (int k0 = 0; k0 < K; k0 += 16) {
        float4 av = *(const float4*)(A + (long)(m0 + ar) * K + k0 + ac);
        As[ac + 0][ar] = av.x; As[ac + 1][ar] = av.y;
        As[ac + 2][ar] = av.z; As[ac + 3][ar] = av.w;
#pragma unroll
        for (int i = 0; i < 4; ++i)
            Bs[br4 + i][bc] = Bm[(long)(k0 + br4 + i) * N + n0 + bc];
        __syncthreads();
#pragma unroll
        for (int kk = 0; kk < 16; ++kk) {
            float a[4], b[4];
#pragma unroll
            for (int i = 0; i < 4; ++i) a[i] = As[kk][ty * 4 + i];
#pragma unroll
            for (int j = 0; j < 4; ++j) b[j] = Bs[kk][tx * 4 + j];
#pragma unroll
            for (int i = 0; i < 4; ++i)
#pragma unroll
                for (int j = 0; j < 4; ++j)
                    acc[i][j] = fmaf(a[i], b[j], acc[i][j]);
        }
        __syncthreads();
    }
#pragma unroll
    for (int i = 0; i < 4; ++i)
#pragma unroll
        for (int j = 0; j < 4; ++j)
            C[(long)(m0 + ty * 4 + i) * N + n0 + tx * 4 + j] =
                acc[i][j] + bias[n0 + tx * 4 + j];
}

// init h,c from BLANK token with zero state; zero scores + padded barrier flags
__global__ void init_kernel(const float* __restrict__ EW, float* __restrict__ h,
                            float* __restrict__ c, float* __restrict__ scores,
                            unsigned int* __restrict__ arrive,
                            unsigned int* __restrict__ release)
{
    int tid = threadIdx.x;
    for (int j = tid; j < HH; j += 256) {
        float gi = EW[j], gg = EW[1280 + j], go = EW[1920 + j];
        float c1 = sigf(gi) * tanhf(gg);
        float h1 = sigf(go) * tanhf(c1);
        for (int b = 0; b < BB; ++b) { h[b * 640 + j] = h1; c[b * 640 + j] = c1; }
    }
    if (tid < 32) scores[tid] = 0.f;
    arrive[tid * 32] = 0u;
    release[tid * 32] = 0u;
}

__global__ __launch_bounds__(256, 1) void decode_kernel(
    const float* __restrict__ ENC, const float* __restrict__ EW,
    const float* __restrict__ Wdec, const float* __restrict__ Whh,
    const float* __restrict__ Wout, const float* __restrict__ bout,
    float* __restrict__ h, float* __restrict__ c,
    float* __restrict__ Tt, float* __restrict__ G,
    unsigned long long* __restrict__ pmax, float* __restrict__ psum,
    float* __restrict__ scores, float* __restrict__ out,
    unsigned int* arrive, unsigned int* release)
{
    __shared__ float Wa[640 * 16];          // 40 KB: 16 cols of [W_dec|W_hh], layout [k][16]
    __shared__ float Wo[640 * 4];           // 10 KB: 4 cols of W_out, layout [k][4]
    __shared__ unsigned long long red_m[4];
    __shared__ float red_s[4];
    __shared__ int s_tok, s_emit;

    int w = blockIdx.x, tid = threadIdx.x;

    // ---- stage weights to LDS (once) ----
    if (w < 200) {
        if (w < 40) {
            const float* src = Wdec + w * 16;
            for (int i = tid; i < 640 * 16; i += 256) {
                int k = i >> 4, cc = i & 15;
                Wa[i] = src[k * 640 + cc];
            }
        } else {
            const float* src = Whh + (w * 16 - 640);
            for (int i = tid; i < 640 * 16; i += 256) {
                int k = i >> 4, cc = i & 15;
                Wa[i] = src[k * 2560 + cc];
            }
        }
    }
    {
        const float* src = Wout + w * 4;
        for (int i = tid; i < 640 * 4; i += 256) {
            int k = i >> 2, cc = i & 3;
            Wo[i] = src[k * 1024 + cc];
        }
    }
    __syncthreads();

    unsigned int bk = 0;

    for (int t = 0; t < TT; ++t) {
        // ---- Phase A: u = h @ [W_dec|W_hh]; Tt = tanh(ENC+u_dec), G = u_hh ----
        if (w < 200) {
            int b = tid >> 3, cg = tid & 7;
            int lc = cg * 2;
            const float* hb = h + b * 640;
            float a0 = 0.f, a1 = 0.f;
            for (int k0 = 0; k0 < 640; k0 += 4) {
                float4 hv = *(const float4*)(hb + k0);
                float hl[4] = {hv.x, hv.y, hv.z, hv.w};
#pragma unroll
                for (int j = 0; j < 4; ++j) {
                    float2 wv = *(const float2*)(&Wa[(k0 + j) * 16 + lc]);
                    a0 = fmaf(hl[j], wv.x, a0);
                    a1 = fmaf(hl[j], wv.y, a1);
                }
            }
            int gc = w * 16 + lc;
            if (gc < 640) {
                const float* e = ENC + ((long)b * TT + t) * 640;
                Tt[b * 640 + gc]     = tanhf(e[gc] + a0);
                Tt[b * 640 + gc + 1] = tanhf(e[gc + 1] + a1);
            } else {
                G[b * 2560 + gc - 640]     = a0;
                G[b * 2560 + gc - 640 + 1] = a1;
            }
        }
        gbar(arrive, release, w, tid, ++bk);

        // ---- Phase B: logits slice + per-WG argmax/sumexp partials ----
        {
            int half = tid & 1, p = tid >> 1, b = p >> 2, cl = p & 3;
            const float* tb = Tt + b * 640 + half * 320;
            const float* wb = Wo + half * 1280 + cl;
            float acc = 0.f;
            for (int k0 = 0; k0 < 320; k0 += 4) {
                float4 tv = *(const float4*)(tb + k0);
                acc = fmaf(tv.x, wb[(k0 + 0) * 4], acc);
                acc = fmaf(tv.y, wb[(k0 + 1) * 4], acc);
                acc = fmaf(tv.z, wb[(k0 + 2) * 4], acc);
                acc = fmaf(tv.w, wb[(k0 + 3) * 4], acc);
            }
            float oth = __shfl_xor(acc, 1);
            int col = w * 4 + cl;
            float logit = acc + oth + bout[col];
            float sexp = expf(logit);
            unsigned long long pk =
                ((unsigned long long)fkey(logit) << 32) | (unsigned int)(1023 - col);
            unsigned long long o;
            o = shflxor_u64(pk, 2); if (o > pk) pk = o; sexp += __shfl_xor(sexp, 2);
            o = shflxor_u64(pk, 4); if (o > pk) pk = o; sexp += __shfl_xor(sexp, 4);
            if ((tid & 7) == 0) {
                pmax[b * 256 + w] = pk;
                psum[b * 256 + w] = sexp;
            }
        }
        gbar(arrive, release, w, tid, ++bk);

        // ---- Phase C: reduce partials, emit token, LSTM update ----
        if (w < 32) {
            int b = w;
            unsigned long long m = pmax[b * 256 + tid];
            float s = psum[b * 256 + tid];
#pragma unroll
            for (int mask = 1; mask <= 32; mask <<= 1) {
                unsigned long long o = shflxor_u64(m, mask);
                if (o > m) m = o;
                s += __shfl_xor(s, mask);
            }
            if ((tid & 63) == 0) { red_m[tid >> 6] = m; red_s[tid >> 6] = s; }
            __syncthreads();
            if (tid == 0) {
                unsigned long long mm = red_m[0];
                float ss = red_s[0];
#pragma unroll
                for (int i = 1; i < 4; ++i) {
                    if (red_m[i] > mm) mm = red_m[i];
                    ss += red_s[i];
                }
                int tok = 1023 - (int)(mm & 0xFFFFFFFFu);
                unsigned int key = (unsigned int)(mm >> 32);
                unsigned int u = (key & 0x80000000u) ? (key ^ 0x80000000u) : ~key;
                float maxlogit = __uint_as_float(u);
                int emit = (tok != 0);
                out[b * TT + t] = (float)tok;
                if (emit) scores[b] += maxlogit - logf(ss);
                s_tok = tok; s_emit = emit;
            }
            __syncthreads();
            if (s_emit) {
                const float* ew = EW + (long)s_tok * 2560;
                const float* gb = G + b * 2560;
                for (int j = tid; j < 640; j += 256) {
                    float gi = ew[j] + gb[j];
                    float gf = ew[640 + j] + gb[640 + j];
                    float gg = ew[1280 + j] + gb[1280 + j];
                    float go = ew[1920 + j] + gb[1920 + j];
                    float cn = sigf(gf) * c[b * 640 + j] + sigf(gi) * tanhf(gg);
                    float hn = sigf(go) * tanhf(cn);
                    c[b * 640 + j] = cn;
                    h[b * 640 + j] = hn;
                }
            }
        }
        gbar(arrive, release, w, tid, ++bk);
    }

    if (w == 0 && tid == 0) {
        float s = 0.f;
        for (int b = 0; b < 32; ++b) s += expf(scores[b]);
        out[16000] = s / 32.0f;
    }
}

extern "C" void kernel_launch(void* const* d_in, const int* in_sizes, int n_in,
                              void* d_out, int out_size, void* d_ws, size_t ws_size,
                              hipStream_t stream)
{
    const float* X     = (const float*)d_in[0];
    const float* E     = (const float*)d_in[1];
    const float* W_ih  = (const float*)d_in[2];
    const float* W_hh  = (const float*)d_in[3];
    const float* b_l   = (const float*)d_in[4];
    const float* W_enc = (const float*)d_in[5];
    const float* W_dec = (const float*)d_in[6];
    const float* b_j   = (const float*)d_in[7];
    const float* W_out = (const float*)d_in[8];
    const float* b_out = (const float*)d_in[9];

    float* ws  = (float*)d_ws;
    float* ENC = ws;
    float* EW  = ws + 10240000;
    float* h   = ws + 12861440;
    float* c   = ws + 12881920;
    float* Tt  = ws + 12902400;
    float* G   = ws + 12922880;
    unsigned long long* pmax = (unsigned long long*)(ws + 13004800);
    float* psum   = ws + 13021184;
    float* scores = ws + 13029376;
    unsigned int* arrive  = (unsigned int*)(ws + 13029440);
    unsigned int* release = (unsigned int*)(ws + 13037632);
    float* out = (float*)d_out;

    gemm_bias_kernel<<<dim3(10, 250), 256, 0, stream>>>(X, W_enc, b_j, ENC, 16000, 640, 640);
    gemm_bias_kernel<<<dim3(40, 16), 256, 0, stream>>>(E, W_ih, b_l, EW, 1024, 2560, 640);
    init_kernel<<<1, 256, 0, stream>>>(EW, h, c, scores, arrive, release);

    void* args[] = {
        (void*)&ENC, (void*)&EW, (void*)&W_dec, (void*)&W_hh,
        (void*)&W_out, (void*)&b_out, (void*)&h, (void*)&c,
        (void*)&Tt, (void*)&G, (void*)&pmax, (void*)&psum,
        (void*)&scores, (void*)&out, (void*)&arrive, (void*)&release
    };
    hipLaunchCooperativeKernel((const void*)decode_kernel, dim3(NWG), dim3(256),
                               args, 0, stream);
}